// Round 2
// 293.399 us; speedup vs baseline: 1.0504x; 1.0504x over previous
//
#include <hip/hip_runtime.h>
#include <hip/hip_fp16.h>
#include <hip/hip_cooperative_groups.h>
#include <math.h>

#define BH_N 96
#define S_N 4096
#define D_N 64
#define TOPK 128
#define NBLK 384            // BH_N * 4 attention sub-blocks
#define UNITS_TOTAL 24576   // 96*4096/16 row-groups of 16 rows

typedef unsigned long long ull;
namespace cg = cooperative_groups;

__device__ __forceinline__ ull orderKey(double d) {
  ull u = (ull)__double_as_longlong(d);
  if (u & 0x8000000000000000ULL) u = ~u;
  else u |= 0x8000000000000000ULL;
  return u;  // monotone: a<b (double) <=> orderKey(a)<orderKey(b)
}

// Shared memory for the sel+attn body. sQ (32*65 f32 = 8320B, dead after
// QK^T) is unioned with sP (32*132 half = 8448B, born at softmax) -> 25.1 KB
// total so even a 64KB-per-CU occupancy budget gives 2 blocks/CU (coop-launch
// check for 384 blocks needs >= 2/CU).
struct SharedMem {
  int red[2][4];
  int redG[4], redT[4], redS[4];
  int s_idx[TOPK];
  __align__(16) float sB[64 * 65];                 // 16640 B
  __align__(16) unsigned char uQP[32 * 132 * 2];   // 8448 B: sQ | sP union
};

// ---------------------------------------------------------------------------
// Phase 2 body: exact top-128 selection (deterministic, ascending-index) +
// attention on 32 q-rows (sub = which 32 of the 128). Identical math to the
// 307.8us-verified attn kernel; selection set identical to top_k semantics
// (ties broken by lowest index). Output is invariant to s_idx ordering.
// ---------------------------------------------------------------------------
__device__ __forceinline__ void sel_attn_body(
    const float* __restrict__ q, const float* __restrict__ k,
    const float* __restrict__ v, const ull* __restrict__ keys,
    float* __restrict__ out, SharedMem& sm, int bh, int sub) {
  const int tid = threadIdx.x;
  const int lane = tid & 63;
  const int wv = tid >> 6;

  ull key[16];
  {
    const ull* kb = keys + (size_t)bh * S_N;
#pragma unroll
    for (int j = 0; j < 16; ++j) key[j] = kb[tid * 16 + j];  // idx = tid*16+j
  }

  // 64-bit threshold binary search; one barrier/iter (double-buffered red)
  ull lo = 0ULL, hi = ~0ULL;
  int p = 0;
  while (lo < hi) {
    ull d = hi - lo;
    ull mid = lo + (d >> 1) + (d & 1ULL);  // ceil midpoint, overflow-safe
    int c = 0;
#pragma unroll
    for (int j = 0; j < 16; ++j) c += __popcll(__ballot(key[j] >= mid));
    if (lane == 0) sm.red[p][wv] = c;
    __syncthreads();
    int total = sm.red[p][0] + sm.red[p][1] + sm.red[p][2] + sm.red[p][3];
    if (total >= TOPK) lo = mid; else hi = mid - 1;
    p ^= 1;
  }
  const ull T = lo;

  // per-wave counts of strictly-greater and ties
  {
    int cgt = 0, ctie = 0;
#pragma unroll
    for (int j = 0; j < 16; ++j) {
      cgt  += __popcll(__ballot(key[j] > T));
      ctie += __popcll(__ballot(key[j] == T));
    }
    if (lane == 0) { sm.redG[wv] = cgt; sm.redT[wv] = ctie; }
  }
  __syncthreads();
  const int need = TOPK - (sm.redG[0] + sm.redG[1] + sm.redG[2] + sm.redG[3]);
  int wTieBase = 0;
#pragma unroll
  for (int w = 0; w < 4; ++w) if (w < wv) wTieBase += sm.redT[w];

  // selection flags; ties ranked in ascending global index = (wv,lane,j)
  const ull below = (1ULL << lane) - 1ULL;
  unsigned selBits = 0;
  {
    int lanesBelowTies = 0;
#pragma unroll
    for (int j = 0; j < 16; ++j)
      lanesBelowTies += __popcll(__ballot(key[j] == T) & below);
    int sameLane = 0;
#pragma unroll
    for (int j = 0; j < 16; ++j) {
      const bool isTie = (key[j] == T);
      const bool sel = (key[j] > T) ||
                       (isTie && (wTieBase + lanesBelowTies + sameLane) < need);
      if (sel) selBits |= (1u << j);
      sameLane += isTie ? 1 : 0;
    }
  }

  // deterministic ascending-index compaction into s_idx (identical in all 4
  // sub-blocks of this bh — no atomics, no ordering races)
  {
    int csel = 0, lanesBelowSel = 0;
#pragma unroll
    for (int j = 0; j < 16; ++j) {
      const ull ms = __ballot((selBits >> j) & 1u);
      csel += __popcll(ms);
      lanesBelowSel += __popcll(ms & below);
    }
    if (lane == 0) sm.redS[wv] = csel;
    __syncthreads();
    int pos = lanesBelowSel;
#pragma unroll
    for (int w = 0; w < 4; ++w) if (w < wv) pos += sm.redS[w];
#pragma unroll
    for (int j = 0; j < 16; ++j) {
      if ((selBits >> j) & 1u) { sm.s_idx[pos] = tid * 16 + j; ++pos; }
    }
  }
  __syncthreads();  // s_idx ready

  // ---------------- attention on 32 selected q-rows -----------------------
  float* sQ = reinterpret_cast<float*>(sm.uQP);
  __half* sP = reinterpret_cast<__half*>(sm.uQP);
  float* sB = sm.sB;

  const size_t base = (size_t)bh * S_N * D_N;
  const int rgrp = tid >> 4;        // 0..15
  const int c4 = (tid & 15) * 4;    // 0..60
  const int rr = tid >> 4;          // 0..15
  const int cc = tid & 15;          // 0..15

  // gather 32 q rows -> sQ
#pragma unroll
  for (int it = 0; it < 2; ++it) {
    int r = it * 16 + rgrp;
    int srow = sm.s_idx[sub * 32 + r];
    float4 val = *reinterpret_cast<const float4*>(q + base + (size_t)srow * D_N + c4);
    sQ[r * 65 + c4 + 0] = val.x; sQ[r * 65 + c4 + 1] = val.y;
    sQ[r * 65 + c4 + 2] = val.z; sQ[r * 65 + c4 + 3] = val.w;
  }

  // QK^T: acc[j][h*4+m] = row (2rr+j) x col (h*64 + cc*4 + m)
  float acc[2][8];
#pragma unroll
  for (int j = 0; j < 2; ++j)
#pragma unroll
    for (int m = 0; m < 8; ++m) acc[j][m] = 0.f;

  for (int h = 0; h < 2; ++h) {
    __syncthreads();  // h=0: sQ writes done; h=1: sB reads of h=0 done
#pragma unroll
    for (int it = 0; it < 4; ++it) {
      int r = it * 16 + rgrp;
      int srow = sm.s_idx[h * 64 + r];
      float4 val = *reinterpret_cast<const float4*>(k + base + (size_t)srow * D_N + c4);
      sB[r * 65 + c4 + 0] = val.x; sB[r * 65 + c4 + 1] = val.y;
      sB[r * 65 + c4 + 2] = val.z; sB[r * 65 + c4 + 3] = val.w;
    }
    __syncthreads();
    for (int kk = 0; kk < 64; kk += 2) {
#pragma unroll
      for (int u = 0; u < 2; ++u) {
        float qv0 = sQ[(2 * rr + 0) * 65 + kk + u];
        float qv1 = sQ[(2 * rr + 1) * 65 + kk + u];
        float kv[4];
#pragma unroll
        for (int m = 0; m < 4; ++m) kv[m] = sB[(cc * 4 + m) * 65 + kk + u];
#pragma unroll
        for (int m = 0; m < 4; ++m) {
          acc[0][h * 4 + m] += qv0 * kv[m];
          acc[1][h * 4 + m] += qv1 * kv[m];
        }
      }
    }
  }

  // softmax over rows 2rr, 2rr+1 (reduce across 16 consecutive lanes = cc)
  float rmax[2], rsum[2];
#pragma unroll
  for (int j = 0; j < 2; ++j) {
    float mx = acc[j][0];
#pragma unroll
    for (int m = 1; m < 8; ++m) mx = fmaxf(mx, acc[j][m]);
    rmax[j] = mx;
  }
#pragma unroll
  for (int mm = 1; mm < 16; mm <<= 1)
#pragma unroll
    for (int j = 0; j < 2; ++j) rmax[j] = fmaxf(rmax[j], __shfl_xor(rmax[j], mm, 64));
#pragma unroll
  for (int j = 0; j < 2; ++j) {
    float sum = 0.f;
#pragma unroll
    for (int m = 0; m < 8; ++m) {
      float pe = __expf(0.125f * (acc[j][m] - rmax[j]));
      acc[j][m] = pe;
      sum += pe;
    }
    rsum[j] = sum;
  }
#pragma unroll
  for (int mm = 1; mm < 16; mm <<= 1)
#pragma unroll
    for (int j = 0; j < 2; ++j) rsum[j] += __shfl_xor(rsum[j], mm, 64);

  __syncthreads();  // UNION GUARD: all sQ reads complete before sP overwrites

#pragma unroll
  for (int j = 0; j < 2; ++j) {
    float rinv = 1.f / rsum[j];
#pragma unroll
    for (int h2 = 0; h2 < 2; ++h2)
#pragma unroll
      for (int m = 0; m < 4; ++m) {
        int col = h2 * 64 + cc * 4 + m;
        sP[(2 * rr + j) * 132 + col] = __float2half_rn(acc[j][h2 * 4 + m] * rinv);
      }
  }

  // PV: acc2[j][m] = out row (2rr+j), d-col (cc*4+m)
  float acc2[2][4];
#pragma unroll
  for (int j = 0; j < 2; ++j)
#pragma unroll
    for (int m = 0; m < 4; ++m) acc2[j][m] = 0.f;

  for (int h = 0; h < 2; ++h) {
    __syncthreads();  // sP writes visible; sB safe to overwrite
#pragma unroll
    for (int it = 0; it < 4; ++it) {
      int r = it * 16 + rgrp;
      int srow = sm.s_idx[h * 64 + r];
      float4 val = *reinterpret_cast<const float4*>(v + base + (size_t)srow * D_N + c4);
      sB[r * 65 + c4 + 0] = val.x; sB[r * 65 + c4 + 1] = val.y;
      sB[r * 65 + c4 + 2] = val.z; sB[r * 65 + c4 + 3] = val.w;
    }
    __syncthreads();
    for (int s2 = 0; s2 < 64; ++s2) {
      int scol = h * 64 + s2;
      float pj0 = __half2float(sP[(2 * rr + 0) * 132 + scol]);
      float pj1 = __half2float(sP[(2 * rr + 1) * 132 + scol]);
      float vm[4];
#pragma unroll
      for (int m = 0; m < 4; ++m) vm[m] = sB[s2 * 65 + cc * 4 + m];
#pragma unroll
      for (int m = 0; m < 4; ++m) {
        acc2[0][m] += pj0 * vm[m];
        acc2[1][m] += pj1 * vm[m];
      }
    }
  }

  // scatter
#pragma unroll
  for (int j = 0; j < 2; ++j) {
    int srow = sm.s_idx[sub * 32 + 2 * rr + j];
    float4 val;
    val.x = acc2[j][0]; val.y = acc2[j][1]; val.z = acc2[j][2]; val.w = acc2[j][3];
    *reinterpret_cast<float4*>(out + base + (size_t)srow * D_N + cc * 4) = val;
  }
}

// ---------------------------------------------------------------------------
// Cooperative fused kernel: phase1 (keys + zero out) -> grid.sync -> phase2.
// ---------------------------------------------------------------------------
__global__ __launch_bounds__(256, 2)
void fused_coop(const float* __restrict__ q, const float* __restrict__ k,
                const float* __restrict__ v, float* __restrict__ out,
                ull* __restrict__ keys) {
  __shared__ SharedMem sm;
  {
    const int bid = blockIdx.x;
    const int tid = threadIdx.x;
    float4 z; z.x = z.y = z.z = z.w = 0.f;
#pragma unroll 1
    for (int u0 = 0; u0 < UNITS_TOTAL / NBLK; u0 += 8) {
      size_t offs[8];
      float4 val[8];
#pragma unroll
      for (int i = 0; i < 8; ++i) {
        const size_t unit = (size_t)bid * (UNITS_TOTAL / NBLK) + (u0 + i);
        offs[i] = unit * 1024 + (size_t)tid * 4;
        val[i] = *reinterpret_cast<const float4*>(q + offs[i]);
      }
#pragma unroll
      for (int i = 0; i < 8; ++i)
        *reinterpret_cast<float4*>(out + offs[i]) = z;
#pragma unroll
      for (int i = 0; i < 8; ++i) {
        double s  = (double)val[i].x + (double)val[i].y + (double)val[i].z + (double)val[i].w;
        double ss = (double)val[i].x * val[i].x + (double)val[i].y * val[i].y +
                    (double)val[i].z * val[i].z + (double)val[i].w * val[i].w;
#pragma unroll
        for (int m = 1; m < 16; m <<= 1) {
          s  += __shfl_xor(s, m, 64);
          ss += __shfl_xor(ss, m, 64);
        }
        if ((tid & 15) == 0) {
          double mean = s * (1.0 / 64.0);
          double var = (ss - s * s * (1.0 / 64.0)) * (1.0 / 63.0);
          if (var < 0.0) var = 0.0;
          const size_t unit = (size_t)bid * (UNITS_TOTAL / NBLK) + (u0 + i);
          keys[unit * 16 + (tid >> 4)] = orderKey(mean + sqrt(var));
        }
      }
    }
  }

  cg::this_grid().sync();  // keys + zeros visible device-wide

  sel_attn_body(q, k, v, keys, out, sm, blockIdx.x >> 2, blockIdx.x & 3);
}

// ---------------------------------------------------------------------------
// Fallback path (non-cooperative, 2 kernels): proven imp_zero + sel_attn.
// ---------------------------------------------------------------------------
__global__ __launch_bounds__(256)
void imp_zero_kernel(const float* __restrict__ q, float* __restrict__ out,
                     ull* __restrict__ keys) {
  const int tid = threadIdx.x;
  const size_t off = (size_t)blockIdx.x * 1024 + (size_t)tid * 4;
  const float4 v = *reinterpret_cast<const float4*>(q + off);
  float4 z; z.x = z.y = z.z = z.w = 0.f;
  *reinterpret_cast<float4*>(out + off) = z;

  double s  = (double)v.x + (double)v.y + (double)v.z + (double)v.w;
  double ss = (double)v.x * v.x + (double)v.y * v.y +
              (double)v.z * v.z + (double)v.w * v.w;
#pragma unroll
  for (int m = 1; m < 16; m <<= 1) {
    s  += __shfl_xor(s, m, 64);
    ss += __shfl_xor(ss, m, 64);
  }
  if ((tid & 15) == 0) {
    double mean = s * (1.0 / 64.0);
    double var = (ss - s * s * (1.0 / 64.0)) * (1.0 / 63.0);
    if (var < 0.0) var = 0.0;
    keys[(size_t)blockIdx.x * 16 + (tid >> 4)] = orderKey(mean + sqrt(var));
  }
}

__global__ __launch_bounds__(256, 2)
void sel_attn_kernel(const float* __restrict__ q, const float* __restrict__ k,
                     const float* __restrict__ v, const ull* __restrict__ keys,
                     float* __restrict__ out) {
  __shared__ SharedMem sm;
  sel_attn_body(q, k, v, keys, out, sm, blockIdx.x >> 2, blockIdx.x & 3);
}

extern "C" void kernel_launch(void* const* d_in, const int* in_sizes, int n_in,
                              void* d_out, int out_size, void* d_ws, size_t ws_size,
                              hipStream_t stream) {
  const float* q = (const float*)d_in[0];
  const float* k = (const float*)d_in[1];
  const float* v = (const float*)d_in[2];
  float* out = (float*)d_out;
  ull* keys = (ull*)d_ws;  // 96*4096*8 = 3 MB

  static int coop_ok = -1;  // -1 unknown, 1 works, 0 failed (latched on first,
                            // uncaptured, call so capture never retries a bad path)
  if (coop_ok != 0) {
    void* args[] = {(void*)&q, (void*)&k, (void*)&v, (void*)&out, (void*)&keys};
    hipError_t e = hipLaunchCooperativeKernel((void*)fused_coop, dim3(NBLK),
                                              dim3(256), args, 0, stream);
    if (e == hipSuccess) { coop_ok = 1; return; }
    coop_ok = 0;
    (void)hipGetLastError();  // clear sticky error
  }

  imp_zero_kernel<<<UNITS_TOTAL, 256, 0, stream>>>(q, out, keys);
  sel_attn_kernel<<<NBLK, 256, 0, stream>>>(q, k, v, keys, out);
}